// Round 7
// baseline (451.824 us; speedup 1.0000x reference)
//
#include <hip/hip_runtime.h>
#include <hip/hip_bf16.h>

#define EPS 1e-8f

constexpr int B_   = 8192;
constexpr int IN_  = 2048;
constexpr int OUT_ = 2048;
constexpr int KA_  = IN_ * 6;   // augmented K: [x, basis0..4] per input feature
constexpr int NT_  = KA_ / 64;  // 192 K-tiles of BK=64

typedef __bf16 bf16x8 __attribute__((ext_vector_type(8)));
typedef float  f32x16 __attribute__((ext_vector_type(16)));

__device__ __forceinline__ ushort f2bf(float f) {
    union { float f; uint u; } v; v.f = f;
    uint u = v.u;
    uint r = u + 0x7fffu + ((u >> 16) & 1u);   // RNE
    return (ushort)(r >> 16);
}

__device__ __forceinline__ void gload16(const void* g, void* l) {
    __builtin_amdgcn_global_load_lds(
        (const __attribute__((address_space(1))) void*)g,
        (__attribute__((address_space(3))) void*)l,
        16, 0, 0);
}

// ---------------------------------------------------------------------------
// Stage A: A_aug[b, i*6+c] bf16.  (unchanged, passed R2-R6)
// ---------------------------------------------------------------------------
__global__ __launch_bounds__(256) void stage_a(const float* __restrict__ x,
                                               const float* __restrict__ grid,
                                               ushort* __restrict__ A) {
    __shared__ __attribute__((aligned(16))) ushort pack[1536];
    const int tid = threadIdx.x;
    const int b0  = blockIdx.x * 16;
    const int i0  = blockIdx.y * 256;
    const int i   = i0 + tid;

    float g[5];
#pragma unroll
    for (int j = 0; j < 5; ++j) g[j] = grid[i * 5 + j];

    float r1[9], r2[9];
    {
        int t = 0;
#pragma unroll
        for (int o = 1; o <= 3; ++o) {
#pragma unroll
            for (int j = 0; j < 5 - o; ++j) {
                int i2 = min(j + o, 4);
                int i3 = min(j + o + 1, 4);
                r1[t] = 1.0f / (g[i2] - g[j] + EPS);
                r2[t] = 1.0f / (g[i3] - g[j + 1] + EPS);
                ++t;
            }
        }
    }

    for (int r = 0; r < 16; ++r) {
        const int b = b0 + r;
        float xv = x[(size_t)b * IN_ + i];
        float diff[5], bas[5];
#pragma unroll
        for (int j = 0; j < 5; ++j) {
            diff[j] = xv - g[j];
            bas[j]  = (diff[j] >= 0.0f && diff[j] < 1.0f) ? 1.0f : 0.0f;
        }
        int t = 0;
#pragma unroll
        for (int o = 1; o <= 3; ++o) {
            float nb[4];
#pragma unroll
            for (int j = 0; j < 5 - o; ++j) {
                int i3 = min(j + o + 1, 4);
                float t1 = (diff[j] - g[j]) * r1[t] * bas[j];
                float t2 = (g[i3] - diff[j]) * r2[t] * bas[j + 1];
                nb[j] = t1 + t2;
                ++t;
            }
#pragma unroll
            for (int j = 0; j < 5 - o; ++j) bas[j] = nb[j];
        }

        pack[tid * 6 + 0] = f2bf(xv);
#pragma unroll
        for (int j = 0; j < 5; ++j) pack[tid * 6 + 1 + j] = f2bf(bas[j]);
        __syncthreads();
        {
            const uint* ps = (const uint*)pack;
            uint* pd = (uint*)(A + (size_t)b * KA_ + (size_t)i0 * 6);
#pragma unroll
            for (int j = 0; j < 3; ++j) pd[tid + j * 256] = ps[tid + j * 256];
        }
        __syncthreads();
    }
}

// ---------------------------------------------------------------------------
// Stage W: W_aug[o, i*6+c] bf16.  (unchanged, passed R2-R6)
// ---------------------------------------------------------------------------
__global__ __launch_bounds__(256) void stage_w(const float* __restrict__ bw,
                                               const float* __restrict__ sw,
                                               ushort* __restrict__ W) {
    __shared__ __attribute__((aligned(16))) float  ssh[1280];
    __shared__ __attribute__((aligned(16))) ushort wsh[1536];
    const int tid = threadIdx.x;
    const int o   = blockIdx.x;
    const int i0  = blockIdx.y * 256;

    const float* sp = sw + ((size_t)o * IN_ + i0) * 5;
    for (int j = tid; j < 1280; j += 256) ssh[j] = sp[j];
    float bwv = bw[(size_t)o * IN_ + i0 + tid];
    __syncthreads();

    wsh[tid * 6] = f2bf(bwv);
#pragma unroll
    for (int j = 0; j < 5; ++j) wsh[tid * 6 + 1 + j] = f2bf(ssh[tid * 5 + j]);
    __syncthreads();

    const uint* ps = (const uint*)wsh;
    uint* pd = (uint*)(W + (size_t)o * KA_ + (size_t)i0 * 6);
#pragma unroll
    for (int j = 0; j < 3; ++j) pd[tid + j * 256] = ps[tid + j * 256];
}

// ---------------------------------------------------------------------------
// GEMM, 256x256 8-phase, 32x32x16 MFMA (R7):
//   Same skeleton/ledger as R6 (refcheck'd): STAGE schedule, vmcnt(4)@P4/P8,
//   MIDBAR/ENDBAR, T2 swizzle (phys 16B-slot = slot ^ (row&7), both sides).
//   Shape change: per wave 128x64 = 4mblk x 2nblk of 32x32; K-tile 64 =
//   4 kh of 16.  Per phase: 8 independent 32x32x16 MFMAs (one kh), 4-12
//   ds_read_b128.  Halves MFMA instruction count; ceiling 2075->2382 TF.
//   Frag layouts: A/B row(col)=lane&31, k=(lane>>5)*8+e (analog of the
//   verified 16x16 mapping); C/D col=lane&31, row=(reg&3)+8*(reg>>2)+
//   4*(lane>>5)  [m74/m101-verified].
//   Read schedule (front-loaded to keep R6's hazard ledger):
//     P1: all 8 B-frags(Ws0) + A(kh0)   P2-P4: A(kh1..3)   [As0/Ws0 @ t0]
//     P5: all 8 B-frags(Ws1) + A(kh0)   P6-P8: A(kh1..3)   [As1/Ws1 @ t1]
//   Hazards: Ws0 reads end P1, staged P3 (2 barriers); As0 reads end
//   P4-drain, staged P5 (ENDBAR between every wave's lgkm-drain and any
//   STAGE issue); vmcnt ledger identical to R6 (walked: P4 lands
//   prevP7/P8+P1/P2; P8 lands P3..P6).
// grid: 256 blocks (1/CU), XCD-swizzled (256%8==0 -> bijective)
// ---------------------------------------------------------------------------
__global__ __launch_bounds__(512, 2) void gemm_kan8(const ushort* __restrict__ A,
                                                    const ushort* __restrict__ W,
                                                    const float* __restrict__ bias,
                                                    float* __restrict__ out) {
    __shared__ __attribute__((aligned(16))) char lds[2][2][32768];

    const int tid  = threadIdx.x;
    const int lane = tid & 63;
    const int wave = tid >> 6;
    const int wr   = wave >> 2;   // 0..1
    const int wc   = wave & 3;    // 0..3

    uint bid = blockIdx.x;
    uint swz = (bid & 7u) * 32u + (bid >> 3);   // XCD-contiguous chunks
    const int bm = (int)(swz >> 3);             // 0..31
    const int bn = (int)(swz & 7u);             // 0..7

    const uint l5   = ((uint)lane >> 5) * 16u;  // k-half byte offset
    const uint swx  = ((uint)lane & 7u) << 4;   // (row&7)<<4, row&7 == lane&7
    uint aro[4], wro[2];
#pragma unroll
    for (int m = 0; m < 4; ++m) aro[m] = (uint)(wr * 128 + m * 32 + (lane & 31)) * 128u;
#pragma unroll
    for (int n = 0; n < 2; ++n) wro[n] = (uint)(wc * 64 + n * 32 + (lane & 31)) * 128u;

    // staging: LDS row c*8+(l>>3), phys slot l&7; global source col
    // (l&7)^((l>>3)&7)  [same 128B segment, lane-permuted]
    const uint srow0 = (uint)wave * 8u + ((uint)lane >> 3);
    const uint srow1 = srow0 + 64u;
    const uint gcol  = (((uint)lane & 7u) ^ (((uint)lane >> 3) & 7u)) * 8u;
    const ushort* pA0 = A + (size_t)bm * 256 * KA_ + (size_t)srow0 * KA_ + gcol;
    const ushort* pA1 = A + (size_t)bm * 256 * KA_ + (size_t)srow1 * KA_ + gcol;
    const ushort* pW0 = W + (size_t)bn * 256 * KA_ + (size_t)srow0 * KA_ + gcol;
    const ushort* pW1 = W + (size_t)bn * 256 * KA_ + (size_t)srow1 * KA_ + gcol;
    const uint c0off = (uint)wave * 1024u;
    const uint c1off = c0off + 8192u;

    f32x16 acc[4][2];
#pragma unroll
    for (int m = 0; m < 4; ++m)
#pragma unroll
        for (int n = 0; n < 2; ++n)
            acc[m][n] = (f32x16)(0.0f);

#define DSR32(base, ro, kh) (*(const bf16x8*)((base) + (ro) + (((kh) * 32u + l5) ^ swx)))

#define STAGE(s, mat, h, kk, PT0, PT1) do {                                   \
        uint kc_ = (uint)((kk) < NT_ ? (kk) : 0);                             \
        size_t go_ = (size_t)(h) * 128 * KA_ + (size_t)kc_ * 64;              \
        gload16(PT0 + go_, &lds[s][mat][(h) * 16384 + c0off]);                \
        gload16(PT1 + go_, &lds[s][mat][(h) * 16384 + c1off]);                \
    } while (0)

#define RDA32(dst, base, kh) do {                                             \
        _Pragma("unroll") for (int m_ = 0; m_ < 4; ++m_)                      \
            dst[m_] = DSR32(base, aro[m_], kh); } while (0)

#define RDB32(dst, base) do {                                                 \
        _Pragma("unroll") for (int n_ = 0; n_ < 2; ++n_)                      \
        _Pragma("unroll") for (int k_ = 0; k_ < 4; ++k_)                      \
            dst[n_][k_] = DSR32(base, wro[n_], k_); } while (0)

#define MIDBAR() do { __builtin_amdgcn_s_barrier();                           \
        asm volatile("s_waitcnt lgkmcnt(0)" ::: "memory");                    \
        __builtin_amdgcn_sched_barrier(0); } while (0)

// 8 independent 32x32x16 MFMAs (one kh), all on distinct accumulators
#define MFMA8(AF, BF, KH) do {                                                \
        __builtin_amdgcn_s_setprio(1);                                        \
        _Pragma("unroll") for (int m_ = 0; m_ < 4; ++m_)                      \
        _Pragma("unroll") for (int n_ = 0; n_ < 2; ++n_)                      \
            acc[m_][n_] = __builtin_amdgcn_mfma_f32_32x32x16_bf16(            \
                AF[m_], BF[n_][KH], acc[m_][n_], 0, 0, 0);                    \
        __builtin_amdgcn_s_setprio(0); } while (0)

#define ENDBAR() __builtin_amdgcn_s_barrier()

    const char* As0 = lds[0][0]; const char* Ws0 = lds[0][1];
    const char* As1 = lds[1][0]; const char* Ws1 = lds[1][1];

    // prologue: slot0 <- tile0 (A+W), slot1.W <- tile1
    STAGE(0, 0, 0, 0, pA0, pA1);
    STAGE(0, 0, 1, 0, pA0, pA1);
    STAGE(0, 1, 0, 0, pW0, pW1);
    STAGE(0, 1, 1, 0, pW0, pW1);
    STAGE(1, 1, 0, 1, pW0, pW1);
    STAGE(1, 1, 1, 1, pW0, pW1);
    asm volatile("s_waitcnt vmcnt(4)" ::: "memory");
    __builtin_amdgcn_s_barrier();

    bf16x8 a[4], b[2][4];

    for (int it = 0; it < NT_ / 2; ++it) {
        const int t1 = 2 * it + 1;
        // P1: all B(Ws0,t0) + A(kh0); STAGE As1.lo(t1)
        RDA32(a, As0, 0); RDB32(b, Ws0);
        STAGE(1, 0, 0, t1, pA0, pA1);
        MIDBAR(); MFMA8(a, b, 0); ENDBAR();
        // P2: A(kh1); STAGE As1.hi(t1)
        RDA32(a, As0, 1);
        STAGE(1, 0, 1, t1, pA0, pA1);
        MIDBAR(); MFMA8(a, b, 1); ENDBAR();
        // P3: A(kh2); STAGE Ws0.lo(t0+2)
        RDA32(a, As0, 2);
        STAGE(0, 1, 0, t1 + 1, pW0, pW1);
        MIDBAR(); MFMA8(a, b, 2); ENDBAR();
        // P4: A(kh3); STAGE Ws0.hi(t0+2); vmcnt(4) -> Ws1(prev)+As1 landed
        RDA32(a, As0, 3);
        STAGE(0, 1, 1, t1 + 1, pW0, pW1);
        asm volatile("s_waitcnt vmcnt(4)" ::: "memory");
        MIDBAR(); MFMA8(a, b, 3); ENDBAR();
        // P5: all B(Ws1,t1) + A(kh0); STAGE As0.lo(t0+2)
        RDA32(a, As1, 0); RDB32(b, Ws1);
        STAGE(0, 0, 0, t1 + 1, pA0, pA1);
        MIDBAR(); MFMA8(a, b, 0); ENDBAR();
        // P6: A(kh1); STAGE As0.hi(t0+2)
        RDA32(a, As1, 1);
        STAGE(0, 0, 1, t1 + 1, pA0, pA1);
        MIDBAR(); MFMA8(a, b, 1); ENDBAR();
        // P7: A(kh2); STAGE Ws1.lo(t1+2)
        RDA32(a, As1, 2);
        STAGE(1, 1, 0, t1 + 2, pW0, pW1);
        MIDBAR(); MFMA8(a, b, 2); ENDBAR();
        // P8: A(kh3); STAGE Ws1.hi(t1+2); vmcnt(4) -> Ws0+As0(t0+2) landed
        RDA32(a, As1, 3);
        STAGE(1, 1, 1, t1 + 2, pW0, pW1);
        asm volatile("s_waitcnt vmcnt(4)" ::: "memory");
        MIDBAR(); MFMA8(a, b, 3); ENDBAR();
    }

    // epilogue: C/D 32x32 layout col=lane&31, row=(reg&3)+8*(reg>>2)+4*(lane>>5)
    const int orow0 = bm * 256 + wr * 128 + ((lane >> 5) << 2);
    const int ocol0 = bn * 256 + wc * 64 + (lane & 31);
#pragma unroll
    for (int n = 0; n < 2; ++n) {
        int c = ocol0 + n * 32;
        float bv = bias[c];
#pragma unroll
        for (int m = 0; m < 4; ++m) {
            int r0 = orow0 + m * 32;
#pragma unroll
            for (int reg = 0; reg < 16; ++reg) {
                int r = r0 + (reg & 3) + ((reg >> 2) << 3);
                out[(size_t)r * OUT_ + c] = acc[m][n][reg] + bv;
            }
        }
    }
#undef DSR32
#undef STAGE
#undef RDA32
#undef RDB32
#undef MIDBAR
#undef MFMA8
#undef ENDBAR
}

// ---------------------------------------------------------------------------
// Fallback (no workspace): correct f32 path
// ---------------------------------------------------------------------------
__global__ __launch_bounds__(256) void kan_fallback(const float* __restrict__ x,
                                                    const float* __restrict__ bw,
                                                    const float* __restrict__ bb,
                                                    const float* __restrict__ sw,
                                                    const float* __restrict__ grid,
                                                    float* __restrict__ out) {
    __shared__ float ash[16 * 384];
    const int tid = threadIdx.x;
    const int o   = blockIdx.x * 256 + tid;
    const int b0  = blockIdx.y * 16;
    float acc[16];
#pragma unroll
    for (int r = 0; r < 16; ++r) acc[r] = 0.0f;

    for (int ic = 0; ic < IN_; ic += 64) {
        __syncthreads();
        for (int p = tid; p < 1024; p += 256) {
            int r = p >> 6, ii = p & 63;
            int i = ic + ii;
            float xv = x[(size_t)(b0 + r) * IN_ + i];
            float g[5];
#pragma unroll
            for (int j = 0; j < 5; ++j) g[j] = grid[i * 5 + j];
            float diff[5], bas[5];
#pragma unroll
            for (int j = 0; j < 5; ++j) {
                diff[j] = xv - g[j];
                bas[j]  = (diff[j] >= 0.0f && diff[j] < 1.0f) ? 1.0f : 0.0f;
            }
#pragma unroll
            for (int oo = 1; oo <= 3; ++oo) {
                float nb[4];
#pragma unroll
                for (int j = 0; j < 5 - oo; ++j) {
                    int i2 = min(j + oo, 4);
                    int i3 = min(j + oo + 1, 4);
                    nb[j] = (diff[j] - g[j]) / (g[i2] - g[j] + EPS) * bas[j]
                          + (g[i3] - diff[j]) / (g[i3] - g[j + 1] + EPS) * bas[j + 1];
                }
#pragma unroll
                for (int j = 0; j < 5 - oo; ++j) bas[j] = nb[j];
            }
            float* ap = &ash[r * 384 + ii * 6];
            ap[0] = xv;
#pragma unroll
            for (int j = 0; j < 5; ++j) ap[1 + j] = bas[j];
        }
        __syncthreads();
        for (int ii = 0; ii < 64; ++ii) {
            int i = ic + ii;
            float w0 = bw[(size_t)o * IN_ + i];
            const float* swp = sw + ((size_t)o * IN_ + i) * 5;
            float w1 = swp[0], w2 = swp[1], w3 = swp[2], w4 = swp[3], w5 = swp[4];
#pragma unroll
            for (int r = 0; r < 16; ++r) {
                const float* a = &ash[r * 384 + ii * 6];
                acc[r] += a[0] * w0 + a[1] * w1 + a[2] * w2
                        + a[3] * w3 + a[4] * w4 + a[5] * w5;
            }
        }
    }
    float bv = bb[o];
#pragma unroll
    for (int r = 0; r < 16; ++r)
        out[(size_t)(b0 + r) * OUT_ + o] = acc[r] + bv;
}

extern "C" void kernel_launch(void* const* d_in, const int* in_sizes, int n_in,
                              void* d_out, int out_size, void* d_ws, size_t ws_size,
                              hipStream_t stream) {
    (void)in_sizes; (void)n_in; (void)out_size;
    const float* x    = (const float*)d_in[0];
    const float* bw   = (const float*)d_in[1];
    const float* bb   = (const float*)d_in[2];
    const float* sw   = (const float*)d_in[3];
    const float* grid = (const float*)d_in[4];
    float* out = (float*)d_out;

    const size_t needA = (size_t)B_ * KA_ * sizeof(ushort);
    const size_t needW = (size_t)OUT_ * KA_ * sizeof(ushort);

    if (ws_size >= needA + needW) {
        ushort* A = (ushort*)d_ws;
        ushort* W = A + (size_t)B_ * KA_;
        stage_a<<<dim3(B_ / 16, IN_ / 256), 256, 0, stream>>>(x, grid, A);
        stage_w<<<dim3(OUT_, IN_ / 256), 256, 0, stream>>>(bw, sw, W);
        gemm_kan8<<<dim3(256), 512, 0, stream>>>(A, W, bb, out);
    } else {
        kan_fallback<<<dim3(OUT_ / 256, B_ / 16), 256, 0, stream>>>(x, bw, bb, sw, grid, out);
    }
}

// Round 9
// 429.170 us; speedup vs baseline: 1.0528x; 1.0528x over previous
//
#include <hip/hip_runtime.h>
#include <hip/hip_bf16.h>

#define EPS 1e-8f

constexpr int B_   = 8192;
constexpr int IN_  = 2048;
constexpr int OUT_ = 2048;
constexpr int KA_  = IN_ * 6;   // augmented K: [x, basis0..4] per input feature
constexpr int NT_  = KA_ / 64;  // 192 K-tiles of BK=64

typedef __bf16 bf16x8 __attribute__((ext_vector_type(8)));
typedef float  f32x4  __attribute__((ext_vector_type(4)));

__device__ __forceinline__ ushort f2bf(float f) {
    union { float f; uint u; } v; v.f = f;
    uint u = v.u;
    uint r = u + 0x7fffu + ((u >> 16) & 1u);   // RNE
    return (ushort)(r >> 16);
}

__device__ __forceinline__ void gload16(const void* g, void* l) {
    __builtin_amdgcn_global_load_lds(
        (const __attribute__((address_space(1))) void*)g,
        (__attribute__((address_space(3))) void*)l,
        16, 0, 0);
}

// ---------------------------------------------------------------------------
// Stage A: A_aug[b, i*6+c] bf16.  (unchanged, passed R2-R7)
// ---------------------------------------------------------------------------
__global__ __launch_bounds__(256) void stage_a(const float* __restrict__ x,
                                               const float* __restrict__ grid,
                                               ushort* __restrict__ A) {
    __shared__ __attribute__((aligned(16))) ushort pack[1536];
    const int tid = threadIdx.x;
    const int b0  = blockIdx.x * 16;
    const int i0  = blockIdx.y * 256;
    const int i   = i0 + tid;

    float g[5];
#pragma unroll
    for (int j = 0; j < 5; ++j) g[j] = grid[i * 5 + j];

    float r1[9], r2[9];
    {
        int t = 0;
#pragma unroll
        for (int o = 1; o <= 3; ++o) {
#pragma unroll
            for (int j = 0; j < 5 - o; ++j) {
                int i2 = min(j + o, 4);
                int i3 = min(j + o + 1, 4);
                r1[t] = 1.0f / (g[i2] - g[j] + EPS);
                r2[t] = 1.0f / (g[i3] - g[j + 1] + EPS);
                ++t;
            }
        }
    }

    for (int r = 0; r < 16; ++r) {
        const int b = b0 + r;
        float xv = x[(size_t)b * IN_ + i];
        float diff[5], bas[5];
#pragma unroll
        for (int j = 0; j < 5; ++j) {
            diff[j] = xv - g[j];
            bas[j]  = (diff[j] >= 0.0f && diff[j] < 1.0f) ? 1.0f : 0.0f;
        }
        int t = 0;
#pragma unroll
        for (int o = 1; o <= 3; ++o) {
            float nb[4];
#pragma unroll
            for (int j = 0; j < 5 - o; ++j) {
                int i3 = min(j + o + 1, 4);
                float t1 = (diff[j] - g[j]) * r1[t] * bas[j];
                float t2 = (g[i3] - diff[j]) * r2[t] * bas[j + 1];
                nb[j] = t1 + t2;
                ++t;
            }
#pragma unroll
            for (int j = 0; j < 5 - o; ++j) bas[j] = nb[j];
        }

        pack[tid * 6 + 0] = f2bf(xv);
#pragma unroll
        for (int j = 0; j < 5; ++j) pack[tid * 6 + 1 + j] = f2bf(bas[j]);
        __syncthreads();
        {
            const uint* ps = (const uint*)pack;
            uint* pd = (uint*)(A + (size_t)b * KA_ + (size_t)i0 * 6);
#pragma unroll
            for (int j = 0; j < 3; ++j) pd[tid + j * 256] = ps[tid + j * 256];
        }
        __syncthreads();
    }
}

// ---------------------------------------------------------------------------
// Stage W: W_aug[o, i*6+c] bf16.  (unchanged, passed R2-R7)
// ---------------------------------------------------------------------------
__global__ __launch_bounds__(256) void stage_w(const float* __restrict__ bw,
                                               const float* __restrict__ sw,
                                               ushort* __restrict__ W) {
    __shared__ __attribute__((aligned(16))) float  ssh[1280];
    __shared__ __attribute__((aligned(16))) ushort wsh[1536];
    const int tid = threadIdx.x;
    const int o   = blockIdx.x;
    const int i0  = blockIdx.y * 256;

    const float* sp = sw + ((size_t)o * IN_ + i0) * 5;
    for (int j = tid; j < 1280; j += 256) ssh[j] = sp[j];
    float bwv = bw[(size_t)o * IN_ + i0 + tid];
    __syncthreads();

    wsh[tid * 6] = f2bf(bwv);
#pragma unroll
    for (int j = 0; j < 5; ++j) wsh[tid * 6 + 1 + j] = f2bf(ssh[tid * 5 + j]);
    __syncthreads();

    const uint* ps = (const uint*)wsh;
    uint* pd = (uint*)(W + (size_t)o * KA_ + (size_t)i0 * 6);
#pragma unroll
    for (int j = 0; j < 3; ++j) pd[tid + j * 256] = ps[tid + j * 256];
}

// ---------------------------------------------------------------------------
// GEMM, 256x256, 4-PHASE schedule (R9): phase-pair merge of the proven R6
//   8-phase.  Per 2 K-tiles: 4 phases x 32 MFMA (vs 8 x 16) -> barrier
//   count halves; per-phase fixed cost (2 bar + lgkm + skew ~260cyc)
//   amortized over 2x MFMA.  Peak live frags 48 VGPR (< R6's 64).
//   PH1(tile0,m0-3): rd a0+all b;  STAGE As1(t1) h0+h1
//   PH2(tile0,m4-7): rd a1;        STAGE Ws0(t0+2);    vmcnt(4)
//   PH3(tile1,m0-3): rd a0+all b;  STAGE As0(t0+2)
//   PH4(tile1,m4-7): rd a1;        STAGE Ws1(t1+2);    vmcnt(4)
//   vmcnt(4)@PH2 drains prevPH4(Ws1)+PH1(As1) -> PH3 reads safe.
//   vmcnt(4)@PH4 drains PH2(Ws0)+PH3(As0) -> next PH1 reads safe.
//   Overwrite gaps are 1 phase, safe WITH ENDBAR: every wave drains its
//   reads at its own MIDBAR-lgkm BEFORE reaching ENDBAR; a stager issues
//   only after passing ENDBAR => after all waves' drains.
//   Per-acc MFMA order identical to R6 -> bitwise-identical output.
//   T2 swizzle: phys 16B-slot = slot ^ (row&7), both-sides involution.
// grid: 256 blocks (1/CU), XCD-swizzled (256%8==0 -> bijective)
// ---------------------------------------------------------------------------
__global__ __launch_bounds__(512, 2) void gemm_kan8(const ushort* __restrict__ A,
                                                    const ushort* __restrict__ W,
                                                    const float* __restrict__ bias,
                                                    float* __restrict__ out) {
    __shared__ __attribute__((aligned(16))) char lds[2][2][32768];

    const int tid  = threadIdx.x;
    const int lane = tid & 63;
    const int wave = tid >> 6;
    const int wr   = wave >> 2;   // 0..1
    const int wc   = wave & 3;    // 0..3

    uint bid = blockIdx.x;
    uint swz = (bid & 7u) * 32u + (bid >> 3);   // XCD-contiguous chunks
    const int bm = (int)(swz >> 3);             // 0..31
    const int bn = (int)(swz & 7u);             // 0..7

    const uint lhi16 = ((uint)lane >> 4) * 16u;
    const uint swx   = ((uint)lane & 7u) << 4;  // (row&7)<<4, row&7 == lane&7
    uint aro[8], wro[4];
#pragma unroll
    for (int m = 0; m < 8; ++m) aro[m] = (uint)(wr * 128 + m * 16 + (lane & 15)) * 128u;
#pragma unroll
    for (int n = 0; n < 4; ++n) wro[n] = (uint)(wc * 64 + n * 16 + (lane & 15)) * 128u;

    // staging: LDS row c*8+(l>>3), phys slot l&7; global source col
    // (l&7)^((l>>3)&7)  [same 128B segment, lane-permuted]
    const uint srow0 = (uint)wave * 8u + ((uint)lane >> 3);
    const uint srow1 = srow0 + 64u;
    const uint gcol  = (((uint)lane & 7u) ^ (((uint)lane >> 3) & 7u)) * 8u;
    const ushort* pA0 = A + (size_t)bm * 256 * KA_ + (size_t)srow0 * KA_ + gcol;
    const ushort* pA1 = A + (size_t)bm * 256 * KA_ + (size_t)srow1 * KA_ + gcol;
    const ushort* pW0 = W + (size_t)bn * 256 * KA_ + (size_t)srow0 * KA_ + gcol;
    const ushort* pW1 = W + (size_t)bn * 256 * KA_ + (size_t)srow1 * KA_ + gcol;
    const uint c0off = (uint)wave * 1024u;
    const uint c1off = c0off + 8192u;

    f32x4 acc[8][4];
#pragma unroll
    for (int m = 0; m < 8; ++m)
#pragma unroll
        for (int n = 0; n < 4; ++n)
            acc[m][n] = (f32x4){0.f, 0.f, 0.f, 0.f};

#define DSR(base, ro, kh) (*(const bf16x8*)((base) + (ro) + (((kh) * 64u + lhi16) ^ swx)))

#define STAGE(s, mat, h, kk, PT0, PT1) do {                                   \
        uint kc_ = (uint)((kk) < NT_ ? (kk) : 0);                             \
        size_t go_ = (size_t)(h) * 128 * KA_ + (size_t)kc_ * 64;              \
        gload16(PT0 + go_, &lds[s][mat][(h) * 16384 + c0off]);                \
        gload16(PT1 + go_, &lds[s][mat][(h) * 16384 + c1off]);                \
    } while (0)

#define RDA(dst, base, mb) do {                                               \
        _Pragma("unroll") for (int m_ = 0; m_ < 4; ++m_) {                    \
            dst[m_][0] = DSR(base, aro[(mb) + m_], 0);                        \
            dst[m_][1] = DSR(base, aro[(mb) + m_], 1); } } while (0)

#define RDB4(dst, base) do {                                                  \
        _Pragma("unroll") for (int n_ = 0; n_ < 4; ++n_) {                    \
            dst[n_][0] = DSR(base, wro[n_], 0);                               \
            dst[n_][1] = DSR(base, wro[n_], 1); } } while (0)

#define MIDBAR() do { __builtin_amdgcn_s_barrier();                           \
        asm volatile("s_waitcnt lgkmcnt(0)" ::: "memory");                    \
        __builtin_amdgcn_sched_barrier(0); } while (0)

// 32 MFMAs: kh-major (16 independent kh0, then 16 kh1); per-acc order
// kh0->kh1, m/n in R6's order -> bitwise identical accumulation.
#define MFMA32(AF, BF, MB) do {                                               \
        __builtin_amdgcn_s_setprio(1);                                        \
        _Pragma("unroll") for (int m_ = 0; m_ < 4; ++m_)                      \
        _Pragma("unroll") for (int n_ = 0; n_ < 4; ++n_)                      \
            acc[(MB)+m_][n_] = __builtin_amdgcn_mfma_f32_16x16x32_bf16(       \
                AF[m_][0], BF[n_][0], acc[(MB)+m_][n_], 0, 0, 0);             \
        _Pragma("unroll") for (int m_ = 0; m_ < 4; ++m_)                      \
        _Pragma("unroll") for (int n_ = 0; n_ < 4; ++n_)                      \
            acc[(MB)+m_][n_] = __builtin_amdgcn_mfma_f32_16x16x32_bf16(       \
                AF[m_][1], BF[n_][1], acc[(MB)+m_][n_], 0, 0, 0);             \
        __builtin_amdgcn_s_setprio(0); } while (0)

#define ENDBAR() __builtin_amdgcn_s_barrier()

    const char* As0 = lds[0][0]; const char* Ws0 = lds[0][1];
    const char* As1 = lds[1][0]; const char* Ws1 = lds[1][1];

    // prologue: slot0 <- tile0 (A+W), slot1.W <- tile1  (12 loads, drain 8)
    STAGE(0, 0, 0, 0, pA0, pA1);
    STAGE(0, 0, 1, 0, pA0, pA1);
    STAGE(0, 1, 0, 0, pW0, pW1);
    STAGE(0, 1, 1, 0, pW0, pW1);
    STAGE(1, 1, 0, 1, pW0, pW1);
    STAGE(1, 1, 1, 1, pW0, pW1);
    asm volatile("s_waitcnt vmcnt(4)" ::: "memory");
    __builtin_amdgcn_s_barrier();

    bf16x8 a0[4][2], a1[4][2], b[4][2];

    for (int it = 0; it < NT_ / 2; ++it) {
        const int t1 = 2 * it + 1;
        // PH1 (tile0, m0-3): reads a0 + all b; STAGE As1(t1) h0+h1
        RDA(a0, As0, 0); RDB4(b, Ws0);
        STAGE(1, 0, 0, t1, pA0, pA1);
        STAGE(1, 0, 1, t1, pA0, pA1);
        MIDBAR(); MFMA32(a0, b, 0); ENDBAR();
        // PH2 (tile0, m4-7): reads a1; STAGE Ws0(t0+2); vmcnt(4)
        RDA(a1, As0, 4);
        STAGE(0, 1, 0, t1 + 1, pW0, pW1);
        STAGE(0, 1, 1, t1 + 1, pW0, pW1);
        asm volatile("s_waitcnt vmcnt(4)" ::: "memory");
        MIDBAR(); MFMA32(a1, b, 4); ENDBAR();
        // PH3 (tile1, m0-3): reads a0 + all b from slot1; STAGE As0(t0+2)
        RDA(a0, As1, 0); RDB4(b, Ws1);
        STAGE(0, 0, 0, t1 + 1, pA0, pA1);
        STAGE(0, 0, 1, t1 + 1, pA0, pA1);
        MIDBAR(); MFMA32(a0, b, 0); ENDBAR();
        // PH4 (tile1, m4-7): reads a1; STAGE Ws1(t1+2); vmcnt(4)
        RDA(a1, As1, 4);
        STAGE(1, 1, 0, t1 + 2, pW0, pW1);
        STAGE(1, 1, 1, t1 + 2, pW0, pW1);
        asm volatile("s_waitcnt vmcnt(4)" ::: "memory");
        MIDBAR(); MFMA32(a1, b, 4); ENDBAR();
    }

    // epilogue: C/D layout col=lane&15, row=(lane>>4)*4+j
    const int orow0 = bm * 256 + wr * 128;
    const int ocol0 = bn * 256 + wc * 64;
#pragma unroll
    for (int n = 0; n < 4; ++n) {
        int c = ocol0 + n * 16 + (lane & 15);
        float bv = bias[c];
#pragma unroll
        for (int m = 0; m < 8; ++m) {
            int r0 = orow0 + m * 16 + ((lane >> 4) << 2);
#pragma unroll
            for (int j = 0; j < 4; ++j)
                out[(size_t)(r0 + j) * OUT_ + c] = acc[m][n][j] + bv;
        }
    }
#undef DSR
#undef STAGE
#undef RDA
#undef RDB4
#undef MIDBAR
#undef MFMA32
#undef ENDBAR
}

// ---------------------------------------------------------------------------
// Fallback (no workspace): correct f32 path
// ---------------------------------------------------------------------------
__global__ __launch_bounds__(256) void kan_fallback(const float* __restrict__ x,
                                                    const float* __restrict__ bw,
                                                    const float* __restrict__ bb,
                                                    const float* __restrict__ sw,
                                                    const float* __restrict__ grid,
                                                    float* __restrict__ out) {
    __shared__ float ash[16 * 384];
    const int tid = threadIdx.x;
    const int o   = blockIdx.x * 256 + tid;
    const int b0  = blockIdx.y * 16;
    float acc[16];
#pragma unroll
    for (int r = 0; r < 16; ++r) acc[r] = 0.0f;

    for (int ic = 0; ic < IN_; ic += 64) {
        __syncthreads();
        for (int p = tid; p < 1024; p += 256) {
            int r = p >> 6, ii = p & 63;
            int i = ic + ii;
            float xv = x[(size_t)(b0 + r) * IN_ + i];
            float g[5];
#pragma unroll
            for (int j = 0; j < 5; ++j) g[j] = grid[i * 5 + j];
            float diff[5], bas[5];
#pragma unroll
            for (int j = 0; j < 5; ++j) {
                diff[j] = xv - g[j];
                bas[j]  = (diff[j] >= 0.0f && diff[j] < 1.0f) ? 1.0f : 0.0f;
            }
#pragma unroll
            for (int oo = 1; oo <= 3; ++oo) {
                float nb[4];
#pragma unroll
                for (int j = 0; j < 5 - oo; ++j) {
                    int i2 = min(j + oo, 4);
                    int i3 = min(j + oo + 1, 4);
                    nb[j] = (diff[j] - g[j]) / (g[i2] - g[j] + EPS) * bas[j]
                          + (g[i3] - diff[j]) / (g[i3] - g[j + 1] + EPS) * bas[j + 1];
                }
#pragma unroll
                for (int j = 0; j < 5 - oo; ++j) bas[j] = nb[j];
            }
            float* ap = &ash[r * 384 + ii * 6];
            ap[0] = xv;
#pragma unroll
            for (int j = 0; j < 5; ++j) ap[1 + j] = bas[j];
        }
        __syncthreads();
        for (int ii = 0; ii < 64; ++ii) {
            int i = ic + ii;
            float w0 = bw[(size_t)o * IN_ + i];
            const float* swp = sw + ((size_t)o * IN_ + i) * 5;
            float w1 = swp[0], w2 = swp[1], w3 = swp[2], w4 = swp[3], w5 = swp[4];
#pragma unroll
            for (int r = 0; r < 16; ++r) {
                const float* a = &ash[r * 384 + ii * 6];
                acc[r] += a[0] * w0 + a[1] * w1 + a[2] * w2
                        + a[3] * w3 + a[4] * w4 + a[5] * w5;
            }
        }
    }
    float bv = bb[o];
#pragma unroll
    for (int r = 0; r < 16; ++r)
        out[(size_t)(b0 + r) * OUT_ + o] = acc[r] + bv;
}

extern "C" void kernel_launch(void* const* d_in, const int* in_sizes, int n_in,
                              void* d_out, int out_size, void* d_ws, size_t ws_size,
                              hipStream_t stream) {
    (void)in_sizes; (void)n_in; (void)out_size;
    const float* x    = (const float*)d_in[0];
    const float* bw   = (const float*)d_in[1];
    const float* bb   = (const float*)d_in[2];
    const float* sw   = (const float*)d_in[3];
    const float* grid = (const float*)d_in[4];
    float* out = (float*)d_out;

    const size_t needA = (size_t)B_ * KA_ * sizeof(ushort);
    const size_t needW = (size_t)OUT_ * KA_ * sizeof(ushort);

    if (ws_size >= needA + needW) {
        ushort* A = (ushort*)d_ws;
        ushort* W = A + (size_t)B_ * KA_;
        stage_a<<<dim3(B_ / 16, IN_ / 256), 256, 0, stream>>>(x, grid, A);
        stage_w<<<dim3(OUT_, IN_ / 256), 256, 0, stream>>>(bw, sw, W);
        gemm_kan8<<<dim3(256), 512, 0, stream>>>(A, W, bb, out);
    } else {
        kan_fallback<<<dim3(OUT_ / 256, B_ / 16), 256, 0, stream>>>(x, bw, bb, sw, grid, out);
    }
}